// Round 6
// baseline (516.124 us; speedup 1.0000x reference)
//
#include <hip/hip_runtime.h>

#define KN 100000
#define KEG 600000
#define KE 600000
#define NB 98  // ceil(KN/1024) scan blocks

using u16 = unsigned short;
typedef __bf16 bf16x8 __attribute__((ext_vector_type(8)));
typedef float f32x4 __attribute__((ext_vector_type(4)));

__device__ __forceinline__ float b2f(u16 u) { return __uint_as_float(((unsigned)u) << 16); }
__device__ __forceinline__ u16 f2b(float f) {
  unsigned u = __float_as_uint(f);
  u += 0x7FFF + ((u >> 16) & 1);  // round-to-nearest-even
  return (u16)(u >> 16);
}
__device__ __forceinline__ int imin(int a, int b) { return a < b ? a : b; }

// ---------------- prep: W-swizzles + zero counts (fused) ----------------
// wm1t: 33 nt x 5 frags x 64 lanes x 8 elem. Frags 0..3 = Wm1 rows 0..127 in
// MFMA B layout; frag 4 = K-extension rows [w128, w129, bm1, 0...].
__global__ __launch_bounds__(256) void k_prep(
    const float* __restrict__ wm1, const float* __restrict__ bm1,
    const float* __restrict__ wm2, const float* __restrict__ w1,
    u16* __restrict__ wm1t, u16* __restrict__ w1t, float* __restrict__ wsc,
    int* counts, int* cursor) {
  int idx = blockIdx.x * 256 + threadIdx.x;
  if (idx < KN) { counts[idx] = 0; cursor[idx] = 0; }
  if (idx < 33 * 5 * 64 * 8) {
    int j = idx & 7;
    int lane = (idx >> 3) & 63;
    int f = (idx >> 9) % 5;
    int nt = idx / (512 * 5);
    int n = nt * 16 + (lane & 15);
    float v = 0.f;
    if (n < 520) {
      if (f < 4) {
        int k = f * 32 + (lane >> 4) * 8 + j;
        v = wm1[k * 520 + n];
      } else {
        int kk = (lane >> 4) * 8 + j;  // 0..31 -> rows 128..159
        if (kk == 0) v = wm1[128 * 520 + n];
        else if (kk == 1) v = wm1[129 * 520 + n];
        else if (kk == 2) v = bm1[n];
      }
    }
    wm1t[idx] = f2b(v);
  }
  if (idx < 33 * 64) {
    int lane = idx & 63, nt = idx >> 6;
    int col = nt * 16 + (lane & 15);
    wsc[idx] = (col < 520) ? wm2[col] : 0.f;
  }
  if (idx < 4 * 2 * 64 * 8) {  // W1 [64k x 64n] -> MFMA B frags (4 nt x 2 kt)
    int j = idx & 7;
    int lane = (idx >> 3) & 63;
    int kt = (idx >> 9) & 1;
    int nt = idx >> 10;
    int n = nt * 16 + (lane & 15);
    int k = kt * 32 + (lane >> 4) * 8 + j;
    w1t[idx] = f2b(w1[k * 64 + n]);
  }
}

// ---------------- CSR build ----------------

__global__ __launch_bounds__(256) void k_hist(const int* __restrict__ gdst, int* __restrict__ counts) {
  int e = blockIdx.x * 256 + threadIdx.x;
  if (e < KEG) atomicAdd(counts + gdst[e], 1);
}

__global__ __launch_bounds__(1024) void k_scan_block(
    const int* __restrict__ counts, int* __restrict__ incl, int* __restrict__ bsum) {
  int gid = blockIdx.x * 1024 + threadIdx.x;
  int lane = threadIdx.x & 63, w = threadIdx.x >> 6;
  int x = (gid < KN) ? counts[gid] : 0;
  for (int off = 1; off < 64; off <<= 1) {
    int y = __shfl_up(x, off);
    if (lane >= off) x += y;
  }
  __shared__ int wtot[16];
  if (lane == 63) wtot[w] = x;
  __syncthreads();
  if (w == 0 && lane < 16) {
    int t = wtot[lane];
    for (int off = 1; off < 16; off <<= 1) {
      int y = __shfl_up(t, off);
      if (lane >= off) t += y;
    }
    wtot[lane] = t;
  }
  __syncthreads();
  if (w > 0) x += wtot[w - 1];
  if (gid < KN) incl[gid] = x;
  if (threadIdx.x == 1023) bsum[blockIdx.x] = x;
}

__global__ __launch_bounds__(64) void k_scan_bsum(const int* __restrict__ bsum, int* __restrict__ boff) {
  int lane = threadIdx.x;
  int x0 = (lane < NB) ? bsum[lane] : 0;
  int x1 = (64 + lane < NB) ? bsum[64 + lane] : 0;
  int i0 = x0, i1 = x1;
  for (int off = 1; off < 64; off <<= 1) {
    int y0 = __shfl_up(i0, off), y1 = __shfl_up(i1, off);
    if (lane >= off) { i0 += y0; i1 += y1; }
  }
  int tot0 = __shfl(i0, 63);
  if (lane < NB) boff[lane] = i0 - x0;
  if (64 + lane < NB) boff[64 + lane] = i1 - x1 + tot0;
}

__global__ __launch_bounds__(1024) void k_scan_final(
    const int* __restrict__ incl, const int* __restrict__ counts,
    const int* __restrict__ boff, int* __restrict__ row_start) {
  int gid = blockIdx.x * 1024 + threadIdx.x;
  if (gid < KN) row_start[gid] = incl[gid] - counts[gid] + boff[blockIdx.x];
}

__global__ __launch_bounds__(256) void k_fill(
    const int* __restrict__ gsrc, const int* __restrict__ gdst,
    const int* __restrict__ row_start, int* __restrict__ cursor, int* __restrict__ csr_src) {
  int e = blockIdx.x * 256 + threadIdx.x;
  if (e >= KEG) return;
  int d = gdst[e];
  int pos = atomicAdd(cursor + d, 1);
  csr_src[row_start[d] + pos] = gsrc[e];
}

// ---------------- GAT layers ----------------

__global__ __launch_bounds__(256) void k_transform0(
    const float* __restrict__ pos, const float* __restrict__ W0,
    const float* __restrict__ att_s, const float* __restrict__ att_d,
    u16* __restrict__ h, float* __restrict__ a_s, float* __restrict__ a_d) {
  int lane = threadIdx.x & 63;
  int n = blockIdx.x * 4 + (threadIdx.x >> 6);
  if (n >= KN) return;
  float p0 = pos[n * 3 + 0], p1 = pos[n * 3 + 1], p2 = pos[n * 3 + 2];
  float hv = p0 * W0[lane] + p1 * W0[64 + lane] + p2 * W0[128 + lane];
  h[n * 64 + lane] = f2b(hv);
  float s = hv * att_s[lane];
  float d = hv * att_d[lane];
  for (int off = 1; off < 64; off <<= 1) { s += __shfl_xor(s, off); d += __shfl_xor(d, off); }
  if (lane == 0) { a_s[n] = s; a_d[n] = d; }
}

// layer1 transform via MFMA: 16 nodes/wave, h = x @ W1 (64x64), fused a_s/a_d.
__global__ __launch_bounds__(256) void k_transform1(
    const u16* __restrict__ x, const u16* __restrict__ w1t,
    const float* __restrict__ att_s, const float* __restrict__ att_d,
    u16* __restrict__ h, float* __restrict__ a_s, float* __restrict__ a_d) {
  int lane = threadIdx.x & 63;
  int wave = threadIdx.x >> 6;
  int nodebase = blockIdx.x * 64 + wave * 16;
  int m = lane & 15, q = lane >> 4;

  int node = imin(nodebase + m, KN - 1);
  const bf16x8* px = (const bf16x8*)(x + node * 64);
  bf16x8 A0 = px[q];      // k 0..31
  bf16x8 A1 = px[q + 4];  // k 32..63

  const bf16x8* bt = (const bf16x8*)w1t;
  float ps[4] = {0.f, 0.f, 0.f, 0.f};
  float pd[4] = {0.f, 0.f, 0.f, 0.f};
#pragma unroll
  for (int nt = 0; nt < 4; ++nt) {
    int col = nt * 16 + m;
    float asv = att_s[col], adv = att_d[col];
    f32x4 acc = {0.f, 0.f, 0.f, 0.f};
    acc = __builtin_amdgcn_mfma_f32_16x16x32_bf16(A0, bt[(nt * 2 + 0) * 64 + lane], acc, 0, 0, 0);
    acc = __builtin_amdgcn_mfma_f32_16x16x32_bf16(A1, bt[(nt * 2 + 1) * 64 + lane], acc, 0, 0, 0);
#pragma unroll
    for (int r = 0; r < 4; ++r) {  // C/D: col=lane&15 -> output col, row=q*4+r -> node
      int rown = nodebase + q * 4 + r;
      if (rown < KN) h[rown * 64 + col] = f2b(acc[r]);
      ps[r] += acc[r] * asv;
      pd[r] += acc[r] * adv;
    }
  }
#pragma unroll
  for (int r = 0; r < 4; ++r) {
    float s = ps[r], d = pd[r];
    s += __shfl_xor(s, 1); d += __shfl_xor(d, 1);
    s += __shfl_xor(s, 2); d += __shfl_xor(d, 2);
    s += __shfl_xor(s, 4); d += __shfl_xor(d, 4);
    s += __shfl_xor(s, 8); d += __shfl_xor(d, 8);
    int rown = nodebase + q * 4 + r;
    if (m == 0 && rown < KN) { a_s[rown] = s; a_d[rown] = d; }
  }
}

// fused scatter-softmax + aggregate + bias + ELU: one wave per dst node, no atomics.
// 2-way unrolled degree loop: two independent gather chains in flight.
__global__ __launch_bounds__(256) void k_gat_agg(
    const int* __restrict__ row_start, const int* __restrict__ counts,
    const int* __restrict__ csr_src, const float* __restrict__ a_s,
    const float* __restrict__ a_d, const u16* __restrict__ h,
    const float* __restrict__ bias, u16* __restrict__ xout) {
  int lane = threadIdx.x & 63;
  int n = blockIdx.x * 4 + (threadIdx.x >> 6);  // grid covers KN exactly
  int start = row_start[n], deg = counts[n];
  float adn = a_d[n];
  float acc = 0.f, den = 0.f;
  int j = 0;
  for (; j + 2 <= deg; j += 2) {
    int s0 = csr_src[start + j];
    int s1 = csr_src[start + j + 1];
    float as0 = a_s[s0], as1 = a_s[s1];
    float h0 = b2f(h[s0 * 64 + lane]);
    float h1 = b2f(h[s1 * 64 + lane]);
    float al0 = as0 + adn; al0 = al0 > 0.f ? al0 : 0.2f * al0;
    float al1 = as1 + adn; al1 = al1 > 0.f ? al1 : 0.2f * al1;
    float ex0 = __expf(al0), ex1 = __expf(al1);
    den += ex0 + ex1;
    acc += ex0 * h0 + ex1 * h1;
  }
  if (j < deg) {
    int s0 = csr_src[start + j];
    float al = a_s[s0] + adn; al = al > 0.f ? al : 0.2f * al;
    float ex = __expf(al);
    den += ex;
    acc += ex * b2f(h[s0 * 64 + lane]);
  }
  float v = acc / (den + 1e-16f) + bias[lane];
  v = v > 0.f ? v : expm1f(v);
  xout[n * 64 + lane] = f2b(v);
}

// ---------------- edge MLP (block-cooperative) ----------------
// Block = 64 edges. A-tile (16x160 per subtile x4) staged once into LDS in MFMA
// fragment order; the 33 n-tiles are split across the block's 4 waves (nt = w,
// w+4, ...) -> 4x shorter per-wave latency chain, 4x less B traffic. Cross-wave
// osum combined via LDS partials. Epilogue: elu(acc)+1 trick, -sum(w2) at end.
__global__ __launch_bounds__(256) void k_edge_mlp(
    const int* __restrict__ eidx, const u16* __restrict__ x2bf,
    const float* __restrict__ eattr, const u16* __restrict__ wm1t,
    const float* __restrict__ wsc, const float* __restrict__ bm2,
    float* __restrict__ out) {
  __shared__ u16 efrag[16 * 512];   // 16 (s,f) fragments x 64 lanes x 8 elem = 16 KB
  __shared__ float part[4][64];
  int t = threadIdx.x;
  int lane = t & 63;
  int wave = t >> 6;
  int base = blockIdx.x * 64;       // 9375 blocks x 64 edges = 600000 exactly
  int m = lane & 15, q = lane >> 4;

  // ---- stage A into fragment-ordered LDS: unit = (f=wave, r=lane) ----
  {
    int f = wave;                   // 0:src-lo 1:src-hi 2:dst-lo 3:dst-hi
    int r = lane;                   // edge row in tile
    int s = r >> 4, mm = r & 15;
    int row = base + r;
    int node = (f < 2) ? eidx[row] : eidx[KE + row];
    const uint4* src = (const uint4*)(x2bf + node * 64 + (f & 1) * 32);
    uint4 v0 = src[0], v1 = src[1], v2 = src[2], v3 = src[3];
    uint4* dst = (uint4*)efrag + (s * 4 + f) * 64 + mm;
    dst[0]  = v0;   // q=0 chunk
    dst[16] = v1;   // q=1
    dst[32] = v2;   // q=2
    dst[48] = v3;   // q=3
  }
  __syncthreads();

  // ---- each wave loads the full A-tile from LDS (lane-contiguous b128) ----
  bf16x8 A[4][4];
  const bf16x8* fr = (const bf16x8*)efrag;
#pragma unroll
  for (int s = 0; s < 4; ++s)
#pragma unroll
    for (int f = 0; f < 4; ++f)
      A[s][f] = fr[(s * 4 + f) * 64 + lane];

  // K-extension fragment: [ea0, ea1, 1, 0...] in lanes q==0
  bf16x8 A5[4];
#pragma unroll
  for (int s = 0; s < 4; ++s) {
    bf16x8 a5 = {0, 0, 0, 0, 0, 0, 0, 0};
    if (q == 0) {
      int row = base + s * 16 + m;
      a5[0] = (__bf16)eattr[row * 2 + 0];
      a5[1] = (__bf16)eattr[row * 2 + 1];
      a5[2] = (__bf16)1.0f;
    }
    A5[s] = a5;
  }

  float osum[4][4];
#pragma unroll
  for (int s = 0; s < 4; ++s)
#pragma unroll
    for (int r = 0; r < 4; ++r) osum[s][r] = 0.f;

  const bf16x8* bt = (const bf16x8*)wm1t;
  float w2tot = 0.f;
  for (int nt = wave; nt < 33; nt += 4) {   // disjoint nt subsets per wave
    bf16x8 B0 = bt[(nt * 5 + 0) * 64 + lane];
    bf16x8 B1 = bt[(nt * 5 + 1) * 64 + lane];
    bf16x8 B2 = bt[(nt * 5 + 2) * 64 + lane];
    bf16x8 B3 = bt[(nt * 5 + 3) * 64 + lane];
    bf16x8 B4 = bt[(nt * 5 + 4) * 64 + lane];
    float w2 = wsc[nt * 64 + lane];
    w2tot += w2;
#pragma unroll
    for (int s = 0; s < 4; ++s) {
      f32x4 acc = {0.f, 0.f, 0.f, 0.f};
      acc = __builtin_amdgcn_mfma_f32_16x16x32_bf16(A[s][0], B0, acc, 0, 0, 0);
      acc = __builtin_amdgcn_mfma_f32_16x16x32_bf16(A[s][1], B1, acc, 0, 0, 0);
      acc = __builtin_amdgcn_mfma_f32_16x16x32_bf16(A[s][2], B2, acc, 0, 0, 0);
      acc = __builtin_amdgcn_mfma_f32_16x16x32_bf16(A[s][3], B3, acc, 0, 0, 0);
      acc = __builtin_amdgcn_mfma_f32_16x16x32_bf16(A5[s],   B4, acc, 0, 0, 0);
#pragma unroll
      for (int r = 0; r < 4; ++r) {
        float lo = fminf(acc[r], 0.f);
        float hi = fmaxf(acc[r], 0.f);
        osum[s][r] += (hi + __expf(lo)) * w2;   // (elu(acc)+1)*w2
      }
    }
  }

  // reduce over the 16 column-lanes, stash per-wave partials
#pragma unroll
  for (int s = 0; s < 4; ++s)
#pragma unroll
    for (int r = 0; r < 4; ++r) {
      float v = osum[s][r] - w2tot;   // undo the +1
      v += __shfl_xor(v, 1);
      v += __shfl_xor(v, 2);
      v += __shfl_xor(v, 4);
      v += __shfl_xor(v, 8);
      if (m == 0) part[wave][s * 16 + q * 4 + r] = v;
    }
  __syncthreads();
  if (t < 64) {
    out[base + t] = part[0][t] + part[1][t] + part[2][t] + part[3][t] + bm2[0];
  }
}

extern "C" void kernel_launch(void* const* d_in, const int* in_sizes, int n_in,
                              void* d_out, int out_size, void* d_ws, size_t ws_size,
                              hipStream_t stream) {
  const float* pos  = (const float*)d_in[0];
  const int* eidx   = (const int*)d_in[1];
  const int* geidx  = (const int*)d_in[2];
  const float* eattr= (const float*)d_in[3];
  const float* W0   = (const float*)d_in[4];
  const float* as0  = (const float*)d_in[5];
  const float* ad0  = (const float*)d_in[6];
  const float* b0   = (const float*)d_in[7];
  const float* W1   = (const float*)d_in[8];
  const float* as1  = (const float*)d_in[9];
  const float* ad1  = (const float*)d_in[10];
  const float* b1   = (const float*)d_in[11];
  const float* Wm1  = (const float*)d_in[12];
  const float* bm1  = (const float*)d_in[13];
  const float* Wm2  = (const float*)d_in[14];
  const float* bm2  = (const float*)d_in[15];
  float* out = (float*)d_out;

  char* ws = (char*)d_ws;
  size_t off = 0;
  auto carve = [&](size_t bytes) {
    char* p = ws + off;
    off = (off + bytes + 255) & ~(size_t)255;
    return p;
  };
  int* counts    = (int*)carve((size_t)KN * 4);
  int* cursor    = (int*)carve((size_t)KN * 4);
  int* incl      = (int*)carve((size_t)KN * 4);
  int* row_start = (int*)carve((size_t)KN * 4);
  int* bsum      = (int*)carve(128 * 4);
  int* boff      = (int*)carve(128 * 4);
  int* csr_src   = (int*)carve((size_t)KEG * 4);
  u16* h         = (u16*)carve((size_t)KN * 64 * 2);
  u16* x12       = (u16*)carve((size_t)KN * 64 * 2);
  float* a_s     = (float*)carve((size_t)KN * 4);
  float* a_d     = (float*)carve((size_t)KN * 4);
  u16* wm1t      = (u16*)carve((size_t)33 * 5 * 64 * 8 * 2);
  u16* w1t       = (u16*)carve((size_t)4 * 2 * 64 * 8 * 2);
  float* wsc     = (float*)carve((size_t)33 * 64 * 4);

  const int* gsrc = geidx;
  const int* gdst = geidx + KEG;

  k_prep<<<(KN + 255) / 256, 256, 0, stream>>>(Wm1, bm1, Wm2, W1, wm1t, w1t, wsc, counts, cursor);
  k_hist<<<(KEG + 255) / 256, 256, 0, stream>>>(gdst, counts);
  k_scan_block<<<NB, 1024, 0, stream>>>(counts, incl, bsum);
  k_scan_bsum<<<1, 64, 0, stream>>>(bsum, boff);
  k_scan_final<<<NB, 1024, 0, stream>>>(incl, counts, boff, row_start);
  k_fill<<<(KEG + 255) / 256, 256, 0, stream>>>(gsrc, gdst, row_start, cursor, csr_src);

  // ---- GAT layer 0 ----
  k_transform0<<<KN / 4, 256, 0, stream>>>(pos, W0, as0, ad0, h, a_s, a_d);
  k_gat_agg<<<KN / 4, 256, 0, stream>>>(row_start, counts, csr_src, a_s, a_d, h, b0, x12);

  // ---- GAT layer 1 ----
  k_transform1<<<(KN + 63) / 64, 256, 0, stream>>>(x12, w1t, as1, ad1, h, a_s, a_d);
  k_gat_agg<<<KN / 4, 256, 0, stream>>>(row_start, counts, csr_src, a_s, a_d, h, b1, x12);

  // ---- fused edge MLP (block-cooperative MFMA, f32 out) ----
  k_edge_mlp<<<KE / 64, 256, 0, stream>>>(eidx, x12, eattr, wm1t, wsc, bm2, out);
}

// Round 7
// 440.707 us; speedup vs baseline: 1.1711x; 1.1711x over previous
//
#include <hip/hip_runtime.h>

#define KN 100000
#define KEG 600000
#define KE 600000
#define NB 98  // ceil(KN/1024) scan blocks
#define LOG2E 1.4426950408889634f
#define LN2 0.6931471805599453f

using u16 = unsigned short;
typedef __bf16 bf16x8 __attribute__((ext_vector_type(8)));
typedef float f32x4 __attribute__((ext_vector_type(4)));

__device__ __forceinline__ float b2f(u16 u) { return __uint_as_float(((unsigned)u) << 16); }
__device__ __forceinline__ u16 f2b(float f) {
  unsigned u = __float_as_uint(f);
  u += 0x7FFF + ((u >> 16) & 1);  // round-to-nearest-even
  return (u16)(u >> 16);
}
__device__ __forceinline__ int imin(int a, int b) { return a < b ? a : b; }
__device__ __forceinline__ float fexp2(float x) {
#if __has_builtin(__builtin_amdgcn_exp2f)
  return __builtin_amdgcn_exp2f(x);
#else
  return __expf(x * LN2);
#endif
}

// ---------------- prep: W-swizzles + zero counts (fused) ----------------
// wm1t: 34 tiles x 5 frags x 512. Tiles 0..32: Wm1 rows 0..127 (frags 0..3) and
// K-ext rows [w128,w129,bm1] (frag 4), ALL SCALED BY LOG2E (so MFMA output is
// pre-activation in log2 units). Tile 33: linear composite c=B160@wm2 in natural
// units, c_hi in col 0 / c_lo in col 1 (filled by k_cvec; zeroed here).
// wsc2: per (nt,lane) float2 {w2, -ln2*w2}.
__global__ __launch_bounds__(256) void k_prep(
    const float* __restrict__ wm1, const float* __restrict__ bm1,
    const float* __restrict__ wm2, const float* __restrict__ w1,
    u16* __restrict__ wm1t, u16* __restrict__ w1t, float2* __restrict__ wsc2,
    int* counts, int* cursor) {
  int idx = blockIdx.x * 256 + threadIdx.x;
  if (idx < KN) { counts[idx] = 0; cursor[idx] = 0; }
  if (idx < 34 * 5 * 512) {
    int j = idx & 7;
    int lane = (idx >> 3) & 63;
    int f = (idx >> 9) % 5;
    int nt = idx / (512 * 5);
    float v = 0.f;
    if (nt < 33) {
      int n = nt * 16 + (lane & 15);
      if (n < 520) {
        if (f < 4) {
          int k = f * 32 + (lane >> 4) * 8 + j;
          v = wm1[k * 520 + n] * LOG2E;
        } else {
          int kk = (lane >> 4) * 8 + j;  // 0..31 -> ext rows
          if (kk == 0) v = wm1[128 * 520 + n] * LOG2E;
          else if (kk == 1) v = wm1[129 * 520 + n] * LOG2E;
          else if (kk == 2) v = bm1[n] * LOG2E;
        }
      }
    }
    wm1t[idx] = f2b(v);
  }
  if (idx < 33 * 64) {
    int lane = idx & 63, nt = idx >> 6;
    int col = nt * 16 + (lane & 15);
    float w2 = (col < 520) ? wm2[col] : 0.f;
    float2 p; p.x = w2; p.y = -LN2 * w2;
    wsc2[idx] = p;
  }
  if (idx < 4 * 2 * 64 * 8) {  // W1 [64k x 64n] -> MFMA B frags (4 nt x 2 kt)
    int j = idx & 7;
    int lane = (idx >> 3) & 63;
    int kt = (idx >> 9) & 1;
    int nt = idx >> 10;
    int n = nt * 16 + (lane & 15);
    int k = kt * 32 + (lane >> 4) * 8 + j;
    w1t[idx] = f2b(w1[k * 64 + n]);
  }
}

// composite linear vector c_k = sum_h B160[k][h]*wm2[h] (natural units), written
// into wm1t tile 33 (c_hi col 0, c_lo col 1). Wave 131 computes w2sum = sum wm2.
__global__ __launch_bounds__(256) void k_cvec(
    const float* __restrict__ wm1, const float* __restrict__ bm1,
    const float* __restrict__ wm2, u16* __restrict__ wm1t, float* __restrict__ w2sum) {
  int lane = threadIdx.x & 63;
  int w = blockIdx.x * 4 + (threadIdx.x >> 6);  // 33 blocks x 4 = 132 waves
  float x = 0.f;
  if (w <= 129) {
    const float* row = wm1 + (size_t)w * 520;
#pragma unroll
    for (int j = 0; j < 8; ++j) x += row[j * 64 + lane] * wm2[j * 64 + lane];
    if (lane < 8) x += row[512 + lane] * wm2[512 + lane];
  } else if (w == 130) {
#pragma unroll
    for (int j = 0; j < 8; ++j) x += bm1[j * 64 + lane] * wm2[j * 64 + lane];
    if (lane < 8) x += bm1[512 + lane] * wm2[512 + lane];
  } else if (w == 131) {
#pragma unroll
    for (int j = 0; j < 8; ++j) x += wm2[j * 64 + lane];
    if (lane < 8) x += wm2[512 + lane];
  }
  for (int off = 1; off < 64; off <<= 1) x += __shfl_xor(x, off);
  if (lane == 0) {
    if (w <= 130) {
      int f = w >> 5, kk = w & 31;
      int qq = kk >> 3, jj = kk & 7;
      u16 chi = f2b(x);
      u16 clo = f2b(x - b2f(chi));
      int bi = (33 * 5 + f) * 512;
      wm1t[bi + (qq * 16 + 0) * 8 + jj] = chi;
      wm1t[bi + (qq * 16 + 1) * 8 + jj] = clo;
    } else if (w == 131) {
      w2sum[0] = x;
    }
  }
}

// ---------------- CSR build ----------------

__global__ __launch_bounds__(256) void k_hist(const int* __restrict__ gdst, int* __restrict__ counts) {
  int e = blockIdx.x * 256 + threadIdx.x;
  if (e < KEG) atomicAdd(counts + gdst[e], 1);
}

__global__ __launch_bounds__(1024) void k_scan_block(
    const int* __restrict__ counts, int* __restrict__ incl, int* __restrict__ bsum) {
  int gid = blockIdx.x * 1024 + threadIdx.x;
  int lane = threadIdx.x & 63, w = threadIdx.x >> 6;
  int x = (gid < KN) ? counts[gid] : 0;
  for (int off = 1; off < 64; off <<= 1) {
    int y = __shfl_up(x, off);
    if (lane >= off) x += y;
  }
  __shared__ int wtot[16];
  if (lane == 63) wtot[w] = x;
  __syncthreads();
  if (w == 0 && lane < 16) {
    int t = wtot[lane];
    for (int off = 1; off < 16; off <<= 1) {
      int y = __shfl_up(t, off);
      if (lane >= off) t += y;
    }
    wtot[lane] = t;
  }
  __syncthreads();
  if (w > 0) x += wtot[w - 1];
  if (gid < KN) incl[gid] = x;
  if (threadIdx.x == 1023) bsum[blockIdx.x] = x;
}

__global__ __launch_bounds__(64) void k_scan_bsum(const int* __restrict__ bsum, int* __restrict__ boff) {
  int lane = threadIdx.x;
  int x0 = (lane < NB) ? bsum[lane] : 0;
  int x1 = (64 + lane < NB) ? bsum[64 + lane] : 0;
  int i0 = x0, i1 = x1;
  for (int off = 1; off < 64; off <<= 1) {
    int y0 = __shfl_up(i0, off), y1 = __shfl_up(i1, off);
    if (lane >= off) { i0 += y0; i1 += y1; }
  }
  int tot0 = __shfl(i0, 63);
  if (lane < NB) boff[lane] = i0 - x0;
  if (64 + lane < NB) boff[64 + lane] = i1 - x1 + tot0;
}

__global__ __launch_bounds__(1024) void k_scan_final(
    const int* __restrict__ incl, const int* __restrict__ counts,
    const int* __restrict__ boff, int* __restrict__ row_start) {
  int gid = blockIdx.x * 1024 + threadIdx.x;
  if (gid < KN) row_start[gid] = incl[gid] - counts[gid] + boff[blockIdx.x];
}

__global__ __launch_bounds__(256) void k_fill(
    const int* __restrict__ gsrc, const int* __restrict__ gdst,
    const int* __restrict__ row_start, int* __restrict__ cursor, int* __restrict__ csr_src) {
  int e = blockIdx.x * 256 + threadIdx.x;
  if (e >= KEG) return;
  int d = gdst[e];
  int pos = atomicAdd(cursor + d, 1);
  csr_src[row_start[d] + pos] = gsrc[e];
}

// ---------------- GAT layers ----------------

__global__ __launch_bounds__(256) void k_transform0(
    const float* __restrict__ pos, const float* __restrict__ W0,
    const float* __restrict__ att_s, const float* __restrict__ att_d,
    u16* __restrict__ h, float* __restrict__ a_s, float* __restrict__ a_d) {
  int lane = threadIdx.x & 63;
  int n = blockIdx.x * 4 + (threadIdx.x >> 6);
  if (n >= KN) return;
  float p0 = pos[n * 3 + 0], p1 = pos[n * 3 + 1], p2 = pos[n * 3 + 2];
  float hv = p0 * W0[lane] + p1 * W0[64 + lane] + p2 * W0[128 + lane];
  h[n * 64 + lane] = f2b(hv);
  float s = hv * att_s[lane];
  float d = hv * att_d[lane];
  for (int off = 1; off < 64; off <<= 1) { s += __shfl_xor(s, off); d += __shfl_xor(d, off); }
  if (lane == 0) { a_s[n] = s; a_d[n] = d; }
}

// layer1 transform via MFMA: 16 nodes/wave, h = x @ W1 (64x64), fused a_s/a_d.
__global__ __launch_bounds__(256) void k_transform1(
    const u16* __restrict__ x, const u16* __restrict__ w1t,
    const float* __restrict__ att_s, const float* __restrict__ att_d,
    u16* __restrict__ h, float* __restrict__ a_s, float* __restrict__ a_d) {
  int lane = threadIdx.x & 63;
  int wave = threadIdx.x >> 6;
  int nodebase = blockIdx.x * 64 + wave * 16;
  int m = lane & 15, q = lane >> 4;

  int node = imin(nodebase + m, KN - 1);
  const bf16x8* px = (const bf16x8*)(x + node * 64);
  bf16x8 A0 = px[q];      // k 0..31
  bf16x8 A1 = px[q + 4];  // k 32..63

  const bf16x8* bt = (const bf16x8*)w1t;
  float ps[4] = {0.f, 0.f, 0.f, 0.f};
  float pd[4] = {0.f, 0.f, 0.f, 0.f};
#pragma unroll
  for (int nt = 0; nt < 4; ++nt) {
    int col = nt * 16 + m;
    float asv = att_s[col], adv = att_d[col];
    f32x4 acc = {0.f, 0.f, 0.f, 0.f};
    acc = __builtin_amdgcn_mfma_f32_16x16x32_bf16(A0, bt[(nt * 2 + 0) * 64 + lane], acc, 0, 0, 0);
    acc = __builtin_amdgcn_mfma_f32_16x16x32_bf16(A1, bt[(nt * 2 + 1) * 64 + lane], acc, 0, 0, 0);
#pragma unroll
    for (int r = 0; r < 4; ++r) {  // C/D: col=lane&15 -> output col, row=q*4+r -> node
      int rown = nodebase + q * 4 + r;
      if (rown < KN) h[rown * 64 + col] = f2b(acc[r]);
      ps[r] += acc[r] * asv;
      pd[r] += acc[r] * adv;
    }
  }
#pragma unroll
  for (int r = 0; r < 4; ++r) {
    float s = ps[r], d = pd[r];
    s += __shfl_xor(s, 1); d += __shfl_xor(d, 1);
    s += __shfl_xor(s, 2); d += __shfl_xor(d, 2);
    s += __shfl_xor(s, 4); d += __shfl_xor(d, 4);
    s += __shfl_xor(s, 8); d += __shfl_xor(d, 8);
    int rown = nodebase + q * 4 + r;
    if (m == 0 && rown < KN) { a_s[rown] = s; a_d[rown] = d; }
  }
}

// fused scatter-softmax + aggregate + bias + ELU: one wave per dst node, no atomics.
// 2-way unrolled degree loop: two independent gather chains in flight.
__global__ __launch_bounds__(256) void k_gat_agg(
    const int* __restrict__ row_start, const int* __restrict__ counts,
    const int* __restrict__ csr_src, const float* __restrict__ a_s,
    const float* __restrict__ a_d, const u16* __restrict__ h,
    const float* __restrict__ bias, u16* __restrict__ xout) {
  int lane = threadIdx.x & 63;
  int n = blockIdx.x * 4 + (threadIdx.x >> 6);  // grid covers KN exactly
  int start = row_start[n], deg = counts[n];
  float adn = a_d[n];
  float acc = 0.f, den = 0.f;
  int j = 0;
  for (; j + 2 <= deg; j += 2) {
    int s0 = csr_src[start + j];
    int s1 = csr_src[start + j + 1];
    float as0 = a_s[s0], as1 = a_s[s1];
    float h0 = b2f(h[s0 * 64 + lane]);
    float h1 = b2f(h[s1 * 64 + lane]);
    float al0 = as0 + adn; al0 = al0 > 0.f ? al0 : 0.2f * al0;
    float al1 = as1 + adn; al1 = al1 > 0.f ? al1 : 0.2f * al1;
    float ex0 = __expf(al0), ex1 = __expf(al1);
    den += ex0 + ex1;
    acc += ex0 * h0 + ex1 * h1;
  }
  if (j < deg) {
    int s0 = csr_src[start + j];
    float al = a_s[s0] + adn; al = al > 0.f ? al : 0.2f * al;
    float ex = __expf(al);
    den += ex;
    acc += ex * b2f(h[s0 * 64 + lane]);
  }
  float v = acc / (den + 1e-16f) + bias[lane];
  v = v > 0.f ? v : expm1f(v);
  xout[n * 64 + lane] = f2b(v);
}

// ---------------- edge MLP ----------------
// Wave = 64 edges (R5 structure). acc2 = pre*log2e via scaled B. Per element:
// t=min(acc2,0); e=exp2(t); osum += e*w2 + t*(-ln2*w2)   [4 VALU ops]
// out = linear + reduce(osum) - w2sum + bm2, linear via extra MFMA tile
// (c_hi col0 + c_lo col1, c = B160@wm2 precomputed).
__global__ __launch_bounds__(256) void k_edge_mlp(
    const int* __restrict__ eidx, const u16* __restrict__ x2bf,
    const float* __restrict__ eattr, const u16* __restrict__ wm1t,
    const float2* __restrict__ wsc2, const float* __restrict__ w2sum,
    const float* __restrict__ bm2, float* __restrict__ out) {
  int lane = threadIdx.x & 63;
  int wave = threadIdx.x >> 6;
  int base = blockIdx.x * 256 + wave * 64;
  int m = lane & 15, q = lane >> 4;

  // A fragments: A[m=lane&15][k=q*8+j]
  bf16x8 A[4][4];
#pragma unroll
  for (int s = 0; s < 4; ++s) {
    int row = imin(base + s * 16 + m, KE - 1);
    int es = eidx[row], ed = eidx[KE + row];
    const bf16x8* psrc = (const bf16x8*)(x2bf + es * 64);
    const bf16x8* pdst = (const bf16x8*)(x2bf + ed * 64);
    A[s][0] = psrc[q];      // k 0..31   (x_src lo)
    A[s][1] = psrc[q + 4];  // k 32..63  (x_src hi)
    A[s][2] = pdst[q];      // k 64..95  (x_dst lo)
    A[s][3] = pdst[q + 4];  // k 96..127 (x_dst hi)
  }

  // K-extension fragment: [ea0, ea1, 1, 0...] in lanes q==0
  bf16x8 A5[4];
#pragma unroll
  for (int s = 0; s < 4; ++s) {
    bf16x8 a5 = {0, 0, 0, 0, 0, 0, 0, 0};
    if (q == 0) {
      int row = imin(base + s * 16 + m, KE - 1);
      a5[0] = (__bf16)eattr[row * 2 + 0];
      a5[1] = (__bf16)eattr[row * 2 + 1];
      a5[2] = (__bf16)1.0f;
    }
    A5[s] = a5;
  }

  float osum[4][4];
#pragma unroll
  for (int s = 0; s < 4; ++s)
#pragma unroll
    for (int r = 0; r < 4; ++r) osum[s][r] = 0.f;

  const bf16x8* bt = (const bf16x8*)wm1t;
#pragma unroll 1
  for (int nt = 0; nt < 33; ++nt) {
    bf16x8 B0 = bt[(nt * 5 + 0) * 64 + lane];
    bf16x8 B1 = bt[(nt * 5 + 1) * 64 + lane];
    bf16x8 B2 = bt[(nt * 5 + 2) * 64 + lane];
    bf16x8 B3 = bt[(nt * 5 + 3) * 64 + lane];
    bf16x8 B4 = bt[(nt * 5 + 4) * 64 + lane];
    float2 w2 = wsc2[nt * 64 + lane];
#pragma unroll
    for (int s = 0; s < 4; ++s) {
      f32x4 acc = {0.f, 0.f, 0.f, 0.f};
      acc = __builtin_amdgcn_mfma_f32_16x16x32_bf16(A[s][0], B0, acc, 0, 0, 0);
      acc = __builtin_amdgcn_mfma_f32_16x16x32_bf16(A[s][1], B1, acc, 0, 0, 0);
      acc = __builtin_amdgcn_mfma_f32_16x16x32_bf16(A[s][2], B2, acc, 0, 0, 0);
      acc = __builtin_amdgcn_mfma_f32_16x16x32_bf16(A[s][3], B3, acc, 0, 0, 0);
      acc = __builtin_amdgcn_mfma_f32_16x16x32_bf16(A5[s],   B4, acc, 0, 0, 0);
#pragma unroll
      for (int r = 0; r < 4; ++r) {
        float t = fminf(acc[r], 0.f);
        float e = fexp2(t);
        osum[s][r] += e * w2.x;    // fma
        osum[s][r] += t * w2.y;    // fma (w2.y = -ln2*w2)
      }
    }
  }

  // linear composite tile (natural units): c_hi in col 0, c_lo in col 1
  bf16x8 L0 = bt[(33 * 5 + 0) * 64 + lane];
  bf16x8 L1 = bt[(33 * 5 + 1) * 64 + lane];
  bf16x8 L2 = bt[(33 * 5 + 2) * 64 + lane];
  bf16x8 L3 = bt[(33 * 5 + 3) * 64 + lane];
  bf16x8 L4 = bt[(33 * 5 + 4) * 64 + lane];
  float w2s = w2sum[0];
  float b2v = bm2[0];

#pragma unroll
  for (int s = 0; s < 4; ++s) {
    f32x4 accL = {0.f, 0.f, 0.f, 0.f};
    accL = __builtin_amdgcn_mfma_f32_16x16x32_bf16(A[s][0], L0, accL, 0, 0, 0);
    accL = __builtin_amdgcn_mfma_f32_16x16x32_bf16(A[s][1], L1, accL, 0, 0, 0);
    accL = __builtin_amdgcn_mfma_f32_16x16x32_bf16(A[s][2], L2, accL, 0, 0, 0);
    accL = __builtin_amdgcn_mfma_f32_16x16x32_bf16(A[s][3], L3, accL, 0, 0, 0);
    accL = __builtin_amdgcn_mfma_f32_16x16x32_bf16(A5[s],   L4, accL, 0, 0, 0);
#pragma unroll
    for (int r = 0; r < 4; ++r) {
      float lin = accL[r] + __shfl_xor(accL[r], 1);  // c_hi part (m=0) + c_lo part (m=1)
      float v = osum[s][r];
      v += __shfl_xor(v, 1);
      v += __shfl_xor(v, 2);
      v += __shfl_xor(v, 4);
      v += __shfl_xor(v, 8);  // sum over the 16 column-lanes
      if (m == 0) {
        int row = base + s * 16 + q * 4 + r;
        if (row < KE) out[row] = v - w2s + lin + b2v;
      }
    }
  }
}

extern "C" void kernel_launch(void* const* d_in, const int* in_sizes, int n_in,
                              void* d_out, int out_size, void* d_ws, size_t ws_size,
                              hipStream_t stream) {
  const float* pos  = (const float*)d_in[0];
  const int* eidx   = (const int*)d_in[1];
  const int* geidx  = (const int*)d_in[2];
  const float* eattr= (const float*)d_in[3];
  const float* W0   = (const float*)d_in[4];
  const float* as0  = (const float*)d_in[5];
  const float* ad0  = (const float*)d_in[6];
  const float* b0   = (const float*)d_in[7];
  const float* W1   = (const float*)d_in[8];
  const float* as1  = (const float*)d_in[9];
  const float* ad1  = (const float*)d_in[10];
  const float* b1   = (const float*)d_in[11];
  const float* Wm1  = (const float*)d_in[12];
  const float* bm1  = (const float*)d_in[13];
  const float* Wm2  = (const float*)d_in[14];
  const float* bm2  = (const float*)d_in[15];
  float* out = (float*)d_out;

  char* ws = (char*)d_ws;
  size_t off = 0;
  auto carve = [&](size_t bytes) {
    char* p = ws + off;
    off = (off + bytes + 255) & ~(size_t)255;
    return p;
  };
  int* counts    = (int*)carve((size_t)KN * 4);
  int* cursor    = (int*)carve((size_t)KN * 4);
  int* incl      = (int*)carve((size_t)KN * 4);
  int* row_start = (int*)carve((size_t)KN * 4);
  int* bsum      = (int*)carve(128 * 4);
  int* boff      = (int*)carve(128 * 4);
  int* csr_src   = (int*)carve((size_t)KEG * 4);
  u16* h         = (u16*)carve((size_t)KN * 64 * 2);
  u16* x12       = (u16*)carve((size_t)KN * 64 * 2);
  float* a_s     = (float*)carve((size_t)KN * 4);
  float* a_d     = (float*)carve((size_t)KN * 4);
  u16* wm1t      = (u16*)carve((size_t)34 * 5 * 512 * 2);
  u16* w1t       = (u16*)carve((size_t)4 * 2 * 64 * 8 * 2);
  float2* wsc2   = (float2*)carve((size_t)33 * 64 * 8);
  float* w2sum   = (float*)carve(256);

  const int* gsrc = geidx;
  const int* gdst = geidx + KEG;

  k_prep<<<(KN + 255) / 256, 256, 0, stream>>>(Wm1, bm1, Wm2, W1, wm1t, w1t, wsc2, counts, cursor);
  k_cvec<<<33, 256, 0, stream>>>(Wm1, bm1, Wm2, wm1t, w2sum);
  k_hist<<<(KEG + 255) / 256, 256, 0, stream>>>(gdst, counts);
  k_scan_block<<<NB, 1024, 0, stream>>>(counts, incl, bsum);
  k_scan_bsum<<<1, 64, 0, stream>>>(bsum, boff);
  k_scan_final<<<NB, 1024, 0, stream>>>(incl, counts, boff, row_start);
  k_fill<<<(KEG + 255) / 256, 256, 0, stream>>>(gsrc, gdst, row_start, cursor, csr_src);

  // ---- GAT layer 0 ----
  k_transform0<<<KN / 4, 256, 0, stream>>>(pos, W0, as0, ad0, h, a_s, a_d);
  k_gat_agg<<<KN / 4, 256, 0, stream>>>(row_start, counts, csr_src, a_s, a_d, h, b0, x12);

  // ---- GAT layer 1 ----
  k_transform1<<<(KN + 63) / 64, 256, 0, stream>>>(x12, w1t, as1, ad1, h, a_s, a_d);
  k_gat_agg<<<KN / 4, 256, 0, stream>>>(row_start, counts, csr_src, a_s, a_d, h, b1, x12);

  // ---- fused edge MLP (MFMA, 4-op epilogue, f32 out) ----
  k_edge_mlp<<<(KE + 255) / 256, 256, 0, stream>>>(eidx, x12, eattr, wm1t, wsc2, w2sum, bm2, out);
}